// Round 15
// baseline (130.676 us; speedup 1.0000x reference)
//
#include <hip/hip_runtime.h>
#include <hip/hip_bf16.h>
#include <stdint.h>

typedef float  f32x4  __attribute__((ext_vector_type(4)));
typedef float  f32x16 __attribute__((ext_vector_type(16)));
typedef _Float16 half8 __attribute__((ext_vector_type(8)));
typedef _Float16 half2v __attribute__((ext_vector_type(2)));
typedef unsigned int uint32;

#define N1 256
#define N2T 32768
#define BQ 512
#define KT 32
#define TILE_B 16384
#define NTILE (N2T/KT)   // 1024

// rowF: k-tile = 16 slabs of 1KB; slab s, lane l: pattern l&31, d=[16s+8*(l>>5),+8)
// memF: slab (2b+ks); lane l: d = 32b+(l&31), pats=[16ks+8*(l>>5),+8)
// pF:   per (tile,qgroup): 2 slabs of 1KB = PV B-frags, identity lane layout

union H4 { _Float16 h[4]; unsigned short s[4]; uint2 u2; };

// ---- prep: Mem f32 -> rowF / memF (f16, fragment-order) + m2 (exact f32) ----
__global__ __launch_bounds__(256) void mhn_prep_k(
    const float* __restrict__ Mem, _Float16* __restrict__ rowF,
    _Float16* __restrict__ memF, float* __restrict__ m2g)
{
  const int t   = blockIdx.x;
  const int tid = threadIdx.x;
  const int a    = tid >> 4;
  const int dblk = tid & 15;
  const int r0i  = 32*t + 2*a;

  const float* p0 = Mem + (size_t)r0i*N1 + dblk*16;
  const float* p1 = p0 + N1;
  float4 x0[4], x1[4];
  #pragma unroll
  for (int i=0;i<4;i++){ x0[i] = *(const float4*)(p0+4*i); x1[i] = *(const float4*)(p1+4*i); }

  float s0=0.f, s1=0.f;
  H4 h0[4], h1[4];
  #pragma unroll
  for (int i=0;i<4;i++){
    s0 += x0[i].x*x0[i].x + x0[i].y*x0[i].y + x0[i].z*x0[i].z + x0[i].w*x0[i].w;
    s1 += x1[i].x*x1[i].x + x1[i].y*x1[i].y + x1[i].z*x1[i].z + x1[i].w*x1[i].w;
    h0[i].h[0]=(_Float16)x0[i].x; h0[i].h[1]=(_Float16)x0[i].y; h0[i].h[2]=(_Float16)x0[i].z; h0[i].h[3]=(_Float16)x0[i].w;
    h1[i].h[0]=(_Float16)x1[i].x; h1[i].h[1]=(_Float16)x1[i].y; h1[i].h[2]=(_Float16)x1[i].z; h1[i].h[3]=(_Float16)x1[i].w;
  }

  {
    char* bF = (char*)rowF + (size_t)t*TILE_B + dblk*1024;
    #pragma unroll
    for (int hi=0; hi<2; hi++){
      uint4 wa, wb;
      wa.x = h0[2*hi].u2.x;   wa.y = h0[2*hi].u2.y;
      wa.z = h0[2*hi+1].u2.x; wa.w = h0[2*hi+1].u2.y;
      wb.x = h1[2*hi].u2.x;   wb.y = h1[2*hi].u2.y;
      wb.z = h1[2*hi+1].u2.x; wb.w = h1[2*hi+1].u2.y;
      *(uint4*)(bF + (2*a  )*16 + hi*512) = wa;
      *(uint4*)(bF + (2*a+1)*16 + hi*512) = wb;
    }
  }

  {
    char* bM = (char*)memF + (size_t)t*TILE_B
             + (size_t)(2*(dblk>>1) + (a>>3))*1024
             + (size_t)((dblk&1)*16 + 32*((a>>2)&1))*16
             + (size_t)(a&3)*4;
    #pragma unroll
    for (int i=0;i<4;i++){
      #pragma unroll
      for (int j=0;j<4;j++){
        *(uint32*)(bM + (4*i+j)*16) = (uint32)h0[i].s[j] | ((uint32)h1[i].s[j] << 16);
      }
    }
  }

  s0 += __shfl_xor(s0,1); s0 += __shfl_xor(s0,2); s0 += __shfl_xor(s0,4); s0 += __shfl_xor(s0,8);
  s1 += __shfl_xor(s1,1); s1 += __shfl_xor(s1,2); s1 += __shfl_xor(s1,4); s1 += __shfl_xor(s1,8);
  if (dblk == 0){ m2g[r0i] = -0.5f*s0; m2g[r0i+1] = -0.5f*s1; }
}

// ---- kernel A: QK + per-tile softmax -> pF fragments + m_t/l_t. No accumulator. ----
__global__ __launch_bounds__(256) void mhn_qk_k(
    const _Float16* __restrict__ rowF, const float* __restrict__ m2g,
    const float* __restrict__ v, _Float16* __restrict__ pF,
    float* __restrict__ mt, float* __restrict__ lt)
{
  const int tid = threadIdx.x;
  const int w   = tid >> 6;
  const int l   = tid & 63;
  const int row = l & 31;
  const int hi  = l >> 5;

  const int bid = blockIdx.x;
  const int qg  = (bid & 3)*4 + w;      // q-group 0..15
  const int t0  = (bid >> 2) * 2;       // tile pair
  const int q0  = qg*32;

  half8 v8[16];
  {
    const float* vp = v + (size_t)(q0 + row)*N1 + 8*hi;
    #pragma unroll
    for (int s=0;s<16;s++){
      const float4 a = *(const float4*)(vp + 16*s);
      const float4 b = *(const float4*)(vp + 16*s + 4);
      half8 hv;
      hv[0]=(_Float16)a.x; hv[1]=(_Float16)a.y; hv[2]=(_Float16)a.z; hv[3]=(_Float16)a.w;
      hv[4]=(_Float16)b.x; hv[5]=(_Float16)b.y; hv[6]=(_Float16)b.z; hv[7]=(_Float16)b.w;
      v8[s]=hv;
    }
  }

  #pragma unroll
  for (int tt=0; tt<2; ++tt){
    const int t = t0 + tt;
    const float* m2p = m2g + t*KT + 4*hi;
    f32x4 m2v[4];
    #pragma unroll
    for (int b=0;b<4;b++) m2v[b] = *(const f32x4*)(m2p + 8*b);

    const char* gR = (const char*)rowF + (size_t)t*TILE_B + (uint32)l*16;
    f32x16 S = (f32x16)(0.f);
    #pragma unroll
    for (int s=0;s<16;s++){
      const half8 a = *(const half8*)(gR + s*1024);
      S = __builtin_amdgcn_mfma_f32_32x32x16_f16(a, v8[s], S, 0,0,0);
    }

    float p[16];
    #pragma unroll
    for (int r=0;r<16;r++) p[r] = S[r] + m2v[r>>2][r&3];

    float tm = p[0];
    #pragma unroll
    for (int r=1;r<16;r++) tm = fmaxf(tm, p[r]);
    tm = fmaxf(tm, __shfl_xor(tm, 32));
    #pragma unroll
    for (int r=0;r<16;r++) p[r] = __expf(p[r] - tm);
    float ps = 0.f;
    #pragma unroll
    for (int r=0;r<16;r++) ps += p[r];
    ps += __shfl_xor(ps, 32);

    // pack to PV B-fragments (same shfl net as before)
    uint32 D[8];
    #pragma unroll
    for (int i=0;i<8;i++){
      union { __fp16 h2 __attribute__((ext_vector_type(2))); uint32 u; } cv;
      cv.h2 = __builtin_amdgcn_cvt_pkrtz(p[2*i], p[2*i+1]);
      D[i] = cv.u;
    }
    uint4 f1, f2;
    {
      const uint32 tD0 = (uint32)__shfl_xor((int)D[0], 32);
      const uint32 tD1 = (uint32)__shfl_xor((int)D[1], 32);
      const uint32 tD2 = (uint32)__shfl_xor((int)D[2], 32);
      const uint32 tD3 = (uint32)__shfl_xor((int)D[3], 32);
      const uint32 tD4 = (uint32)__shfl_xor((int)D[4], 32);
      const uint32 tD5 = (uint32)__shfl_xor((int)D[5], 32);
      const uint32 tD6 = (uint32)__shfl_xor((int)D[6], 32);
      const uint32 tD7 = (uint32)__shfl_xor((int)D[7], 32);
      const bool lo = (hi == 0);
      f1.x = lo ? D[0] : tD2;  f1.y = lo ? D[1] : tD3;
      f1.z = lo ? tD0 : D[2];  f1.w = lo ? tD1 : D[3];
      f2.x = lo ? D[4] : tD6;  f2.y = lo ? D[5] : tD7;
      f2.z = lo ? tD4 : D[6];  f2.w = lo ? tD5 : D[7];
    }
    char* pw = (char*)pF + ((size_t)(t*16 + qg))*2048 + (uint32)l*16;
    *(uint4*)pw          = f1;
    *(uint4*)(pw + 1024) = f2;

    if (hi == 0){
      mt[(size_t)t*BQ + q0 + row] = tm;
      lt[(size_t)t*BQ + q0 + row] = ps;
    }
  }
}

// ---- kernel B: pure PV split-K GEMM + scalar online combine over tiles ----
__global__ __launch_bounds__(256) void mhn_pv_k(
    const _Float16* __restrict__ memF, const _Float16* __restrict__ pF,
    const float* __restrict__ mt, const float* __restrict__ lt,
    __hip_bfloat16* __restrict__ Opart, float* __restrict__ mpart,
    float* __restrict__ lpart, int nt)
{
  const int tid = threadIdx.x;
  const int w   = tid >> 6;
  const int l   = tid & 63;
  const int row = l & 31;
  const int hi  = l >> 5;

  const int nwg = gridDim.x;
  const int bid = blockIdx.x;
  const int s_  = (bid & 7) * (nwg >> 3) + (bid >> 3);
  const int c   = s_ >> 2;
  const int qb  = s_ & 3;
  const int qg  = qb*4 + w;
  const int q0  = qg*32;

  float Mrun = -INFINITY, Lrun = 0.f;
  f32x16 oacc[8];
  #pragma unroll
  for (int b=0;b<8;b++) oacc[b] = (f32x16)(0.f);

  const int tbase = c*nt;
  for (int tti=0; tti<nt; ++tti){
    const int t = tbase + tti;
    const float mtv = mt[(size_t)t*BQ + q0 + row];
    if (__any(mtv > Mrun + 8.0f)){        // defer-max: P contribution bounded by e^8
      const float nm = fmaxf(Mrun, mtv);
      const float sc = __expf(Mrun - nm);
      Lrun *= sc; Mrun = nm;
      #pragma unroll
      for (int b=0;b<8;b++) oacc[b] *= sc;
    }
    const float g32 = __expf(mtv - Mrun);
    Lrun += lt[(size_t)t*BQ + q0 + row] * g32;

    // P fragments: identity lane layout; scale by g (per-lane uniform, f16 pk-mul)
    const char* pw = (const char*)pF + ((size_t)(t*16 + qg))*2048 + (uint32)l*16;
    union PU { uint4 q; half2v h2[4]; half8 h; } pb1, pb2;
    pb1.q = *(const uint4*)pw;
    pb2.q = *(const uint4*)(pw + 1024);
    const _Float16 gh = (_Float16)g32;
    half2v gv; gv[0] = gh; gv[1] = gh;
    #pragma unroll
    for (int i=0;i<4;i++){ pb1.h2[i] *= gv; pb2.h2[i] *= gv; }

    // PV GEMM: 16 MFMAs, A slabs from memF (coalesced 1KB), 1-pair lookahead
    const char* gT = (const char*)memF + (size_t)t*TILE_B + (uint32)l*16;
    half8 A1 = *(const half8*)(gT);
    half8 A2 = *(const half8*)(gT + 1024);
    #pragma unroll
    for (int b=0;b<8;b++){
      half8 nA1, nA2;
      if (b < 7){
        nA1 = *(const half8*)(gT + (2*b+2)*1024);
        nA2 = *(const half8*)(gT + (2*b+3)*1024);
      }
      oacc[b] = __builtin_amdgcn_mfma_f32_32x32x16_f16(A1, pb1.h, oacc[b], 0,0,0);
      oacc[b] = __builtin_amdgcn_mfma_f32_32x32x16_f16(A2, pb2.h, oacc[b], 0,0,0);
      if (b < 7){ A1 = nA1; A2 = nA2; }
    }
  }

  {
    __hip_bfloat16* Op = Opart + (size_t)c*N1*BQ + (q0 + row);
    #pragma unroll
    for (int b=0;b<8;b++){
      #pragma unroll
      for (int r=0;r<16;r++){
        const int d = 32*b + (r&3) + 8*(r>>2) + 4*hi;
        Op[(size_t)d*BQ] = __float2bfloat16(oacc[b][r]);
      }
    }
    if (hi == 0){
      mpart[(size_t)c*BQ + q0 + row] = Mrun;
      lpart[(size_t)c*BQ + q0 + row] = Lrun;
    }
  }
}

// ---- stage A: per-q global softmax stats -> W[c][q] = exp(m_c - M_q), invL[q] ----
__global__ __launch_bounds__(256) void mhn_wprep_k(
    const float* __restrict__ mpart, const float* __restrict__ lpart,
    float* __restrict__ W, float* __restrict__ invL, int nchunk)
{
  __shared__ float sred[4];
  const int q = blockIdx.x;
  const int c = threadIdx.x;
  const int l = c & 63, wv = c >> 6;

  const float m = (c < nchunk) ? mpart[(size_t)c*BQ + q] : -INFINITY;
  const float lv = (c < nchunk) ? lpart[(size_t)c*BQ + q] : 0.f;

  float r = m;
  r = fmaxf(r, __shfl_xor(r,1));  r = fmaxf(r, __shfl_xor(r,2));
  r = fmaxf(r, __shfl_xor(r,4));  r = fmaxf(r, __shfl_xor(r,8));
  r = fmaxf(r, __shfl_xor(r,16)); r = fmaxf(r, __shfl_xor(r,32));
  if (l == 0) sred[wv] = r;
  __syncthreads();
  const float M = fmaxf(fmaxf(sred[0], sred[1]), fmaxf(sred[2], sred[3]));
  __syncthreads();

  const float e = __expf(m - M);
  float s = lv * e;
  s += __shfl_xor(s,1);  s += __shfl_xor(s,2);
  s += __shfl_xor(s,4);  s += __shfl_xor(s,8);
  s += __shfl_xor(s,16); s += __shfl_xor(s,32);
  if (l == 0) sred[wv] = s;
  __syncthreads();

  if (c < nchunk) W[(size_t)c*BQ + q] = e;
  if (c == 0) invL[q] = 1.0f / ((sred[0] + sred[1]) + (sred[2] + sred[3]));
}

// ---- stage B (2 q per thread, vectorized loads) ----
__global__ __launch_bounds__(256) void mhn_wsum_k(
    const float* __restrict__ v, const float* __restrict__ mask,
    const __hip_bfloat16* __restrict__ Opart, const float* __restrict__ W,
    const float* __restrict__ invL, float* __restrict__ out, int nchunk)
{
  const int g  = blockIdx.x*256 + threadIdx.x;
  const int q2 = (g & 255) * 2;
  const int d  = g >> 8;

  const __hip_bfloat16* op = Opart + (size_t)d*BQ + q2;
  const float* wp = W + q2;
  float acc0 = 0.f, acc1 = 0.f;
  #pragma unroll 8
  for (int c2=0; c2<nchunk; c2++){
    const uint32 o2 = *(const uint32*)(op + (size_t)c2*N1*BQ);
    const float2 w2 = *(const float2*)(wp + (size_t)c2*BQ);
    acc0 += __bfloat162float(__hip_bfloat16_raw{(unsigned short)(o2 & 0xffffu)}) * w2.x;
    acc1 += __bfloat162float(__hip_bfloat16_raw{(unsigned short)(o2 >> 16)})     * w2.y;
  }
  const float2 iL = *(const float2*)(invL + q2);
  const size_t oi0 = (size_t)q2*N1 + d;
  const float vv0 = v[oi0], mk0 = mask[oi0];
  const float vv1 = v[oi0 + N1], mk1 = mask[oi0 + N1];
  out[oi0]      = vv0 + 0.5f*(acc0*iL.x - vv0)*mk0;
  out[oi0 + N1] = vv1 + 0.5f*(acc1*iL.y - vv1)*mk1;
}

extern "C" void kernel_launch(void* const* d_in, const int* in_sizes, int n_in,
                              void* d_out, int out_size, void* d_ws, size_t ws_size,
                              hipStream_t stream)
{
  (void)in_sizes; (void)n_in; (void)out_size;
  const float* v    = (const float*)d_in[0];
  const float* mask = (const float*)d_in[1];
  const float* Mem  = (const float*)d_in[2];
  float* out = (float*)d_out;

  // ws: rowF 16M | memF 16M | m2 128K | pF 32M | mt 2M | lt 2M | invL | Opart | mpart | lpart | W
  const size_t rowFB = (size_t)N2T*N1*2;
  const size_t memFB = (size_t)N2T*N1*2;
  const size_t m2B   = (size_t)N2T*4;
  const size_t pFB   = (size_t)N2T*BQ*2;
  const size_t mtB   = (size_t)NTILE*BQ*4;
  const size_t fixedB = rowFB + memFB + m2B + pFB + 2*mtB + (size_t)BQ*4;
  const size_t perChunk = (size_t)BQ*N1*2 + (size_t)BQ*12;
  int nchunk = 64;
  while (nchunk > 4 && fixedB + (size_t)nchunk*perChunk > ws_size) nchunk >>= 1;

  char* wsb = (char*)d_ws;
  _Float16* rowF = (_Float16*)wsb;
  _Float16* memF = (_Float16*)(wsb + rowFB);
  float*    m2g  = (float*)(wsb + rowFB + memFB);
  _Float16* pF   = (_Float16*)(wsb + rowFB + memFB + m2B);
  float*    mt   = (float*)(wsb + rowFB + memFB + m2B + pFB);
  float*    lt   = (float*)(wsb + rowFB + memFB + m2B + pFB + mtB);
  float*    invL = (float*)(wsb + rowFB + memFB + m2B + pFB + 2*mtB);
  char* pb = wsb + fixedB;
  __hip_bfloat16* Opart = (__hip_bfloat16*)pb;
  float* mpart = (float*)(pb + (size_t)nchunk*BQ*N1*2);
  float* lpart = mpart + (size_t)nchunk*BQ;
  float* W     = lpart + (size_t)nchunk*BQ;

  const int nt = (N2T / nchunk) / KT;   // tiles per chunk

  mhn_prep_k<<<dim3(NTILE), dim3(256), 0, stream>>>(Mem, rowF, memF, m2g);
  mhn_qk_k<<<dim3(NTILE*2), dim3(256), 0, stream>>>(rowF, m2g, v, pF, mt, lt);
  mhn_pv_k<<<dim3(4*nchunk), dim3(256), 0, stream>>>(memF, pF, mt, lt, Opart, mpart, lpart, nt);
  mhn_wprep_k<<<dim3(BQ), dim3(256), 0, stream>>>(mpart, lpart, W, invL, nchunk);
  mhn_wsum_k<<<dim3((N1*BQ)/512), dim3(256), 0, stream>>>(v, mask, Opart, W, invL, out, nchunk);
}